// Round 1
// baseline (660.305 us; speedup 1.0000x reference)
//
#include <hip/hip_runtime.h>

#define H 128
#define L 256
#define SB 16      // sequences per block
#define NBLK 128   // 2048 / SB
#define NTHR 512   // 8 waves

typedef _Float16 f16x8 __attribute__((ext_vector_type(8)));
typedef float f32x4 __attribute__((ext_vector_type(4)));

#define MFMA(accv, av, bv) accv = __builtin_amdgcn_mfma_f32_16x16x32_f16(av, bv, accv, 0, 0, 0)

__device__ __forceinline__ float fsig(float x) {
  return __builtin_amdgcn_rcpf(1.f + __builtin_amdgcn_exp2f(-1.44269504089f * x));
}
__device__ __forceinline__ float ftanh(float x) {
  return 2.f * __builtin_amdgcn_rcpf(1.f + __builtin_amdgcn_exp2f(-2.88539008178f * x)) - 1.f;
}

// swizzled f16 LDS index for a [rows][128] tile: element (row,k) -> row*128 + (k ^ ((row&7)<<3))
// (XORs the 16B-chunk index with row&7: spreads the stride-256B column pattern across 8 bank-quads)

__global__ __launch_bounds__(NTHR, 2) void lstm_kernel(
    const float* __restrict__ xg,
    const float* __restrict__ Wih0, const float* __restrict__ Whh0,
    const float* __restrict__ bih0, const float* __restrict__ bhh0,
    const float* __restrict__ Wih1, const float* __restrict__ Whh1,
    const float* __restrict__ bih1, const float* __restrict__ bhh1,
    const float* __restrict__ W1,   const float* __restrict__ b1v,
    const float* __restrict__ W2,   const float* __restrict__ b2v,
    const float* __restrict__ abias,
    float* __restrict__ out_scores)
{
  __shared__ __align__(16) _Float16 Whh1_s[512 * H];   // 128 KB, row-swizzled
  __shared__ __align__(16) float    x_s[SB * L];       // 16 KB
  __shared__ __align__(16) _Float16 h1_s[SB * H];      // 4 KB, swizzled
  __shared__ __align__(16) _Float16 h2_s[SB * H];      // 4 KB, swizzled

  const int tid  = threadIdx.x;
  const int lane = tid & 63;
  const int w    = tid >> 6;       // wave 0..7 : owns hidden units [16w,16w+16)
  const int l15  = lane & 15;
  const int lhi  = lane >> 4;      // 0..3
  const int sb   = blockIdx.x * SB;

  // ---- stage x rows for this block (contiguous chunk) ----
  for (int i = tid; i < SB * L; i += NTHR) x_s[i] = xg[sb * L + i];
  // ---- stage W_hh1 as f16, swizzled ----
  for (int i = tid; i < 512 * H; i += NTHR) {
    int r = i >> 7, k = i & 127;
    Whh1_s[(r << 7) + (k ^ ((r & 7) << 3))] = (_Float16)Whh1[i];
  }
  // ---- zero h state (LDS is poisoned 0xAA) ----
  for (int i = tid; i < SB * H; i += NTHR) { h1_s[i] = (_Float16)0.f; h2_s[i] = (_Float16)0.f; }

  // ---- per-wave register weight fragments (B-operand layout) ----
  // tile n = gate (i,f,g,o); cols = n*128 + 16w + l15 ; k = kk*32 + lhi*8 + j
  f16x8 whh0f[4][4], wih1f[4][4];
  float b0r[4], b1r[4], w0r[4];
  #pragma unroll
  for (int n = 0; n < 4; ++n) {
    const int c = (n << 7) + (w << 4) + l15;
    b0r[n] = bih0[c] + bhh0[c];
    b1r[n] = bih1[c] + bhh1[c];
    w0r[n] = Wih0[c];
    #pragma unroll
    for (int kk = 0; kk < 4; ++kk) {
      const float* p0 = Whh0 + c * H + (kk << 5) + (lhi << 3);
      const float* p1 = Wih1 + c * H + (kk << 5) + (lhi << 3);
      f16x8 f0, f1;
      #pragma unroll
      for (int j = 0; j < 8; ++j) { f0[j] = (_Float16)p0[j]; f1[j] = (_Float16)p1[j]; }
      whh0f[n][kk] = f0;
      wih1f[n][kk] = f1;
    }
  }

  f32x4 c1 = {0.f, 0.f, 0.f, 0.f}, c2 = {0.f, 0.f, 0.f, 0.f};
  const int r0   = lhi << 2;          // seq rows (lane>>4)*4 + r   (C/D layout)
  const int colh = (w << 4) | l15;    // hid col this lane writes

  __syncthreads();

  #pragma unroll 1
  for (int t = 0; t < L; ++t) {
    // ================= layer 0 =================
    float xv[4];
    #pragma unroll
    for (int r = 0; r < 4; ++r) xv[r] = x_s[((r0 + r) << 8) + t];  // broadcast reads

    f32x4 acc[4];
    #pragma unroll
    for (int n = 0; n < 4; ++n)
      #pragma unroll
      for (int r = 0; r < 4; ++r) acc[n][r] = xv[r] * w0r[n] + b0r[n];

    #pragma unroll
    for (int kk = 0; kk < 4; ++kk) {
      const int kb = (kk << 5) + (lhi << 3);
      f16x8 a = *(const f16x8*)&h1_s[(l15 << 7) + (kb ^ ((l15 & 7) << 3))];
      MFMA(acc[0], a, whh0f[0][kk]);
      MFMA(acc[1], a, whh0f[1][kk]);
      MFMA(acc[2], a, whh0f[2][kk]);
      MFMA(acc[3], a, whh0f[3][kk]);
    }

    float h1n[4];
    #pragma unroll
    for (int r = 0; r < 4; ++r) {
      float ig = fsig(acc[0][r]), fg = fsig(acc[1][r]);
      float gg = ftanh(acc[2][r]), og = fsig(acc[3][r]);
      float c = fg * c1[r] + ig * gg;
      c1[r] = c;
      h1n[r] = og * ftanh(c);
    }

    __syncthreads();   // everyone done reading h1_s(t-1)
    #pragma unroll
    for (int r = 0; r < 4; ++r) {
      int row = r0 + r;
      h1_s[(row << 7) + (colh ^ ((row & 7) << 3))] = (_Float16)h1n[r];
    }
    __syncthreads();   // h1_s(t) visible

    // ================= layer 1 =================
    #pragma unroll
    for (int n = 0; n < 4; ++n)
      #pragma unroll
      for (int r = 0; r < 4; ++r) acc[n][r] = b1r[n];

    #pragma unroll
    for (int kk = 0; kk < 4; ++kk) {
      const int kb = (kk << 5) + (lhi << 3);
      f16x8 a = *(const f16x8*)&h1_s[(l15 << 7) + (kb ^ ((l15 & 7) << 3))];
      MFMA(acc[0], a, wih1f[0][kk]);
      MFMA(acc[1], a, wih1f[1][kk]);
      MFMA(acc[2], a, wih1f[2][kk]);
      MFMA(acc[3], a, wih1f[3][kk]);
    }
    #pragma unroll
    for (int kk = 0; kk < 4; ++kk) {
      const int kb = (kk << 5) + (lhi << 3);
      f16x8 a = *(const f16x8*)&h2_s[(l15 << 7) + (kb ^ ((l15 & 7) << 3))];
      #pragma unroll
      for (int n = 0; n < 4; ++n) {
        const int c = (n << 7) + (w << 4) + l15;
        f16x8 b = *(const f16x8*)&Whh1_s[(c << 7) + (kb ^ ((c & 7) << 3))];
        MFMA(acc[n], a, b);
      }
    }

    float h2n[4];
    #pragma unroll
    for (int r = 0; r < 4; ++r) {
      float ig = fsig(acc[0][r]), fg = fsig(acc[1][r]);
      float gg = ftanh(acc[2][r]), og = fsig(acc[3][r]);
      float c = fg * c2[r] + ig * gg;
      c2[r] = c;
      h2n[r] = og * ftanh(c);
    }

    __syncthreads();   // everyone done reading h2_s(t-1)
    #pragma unroll
    for (int r = 0; r < 4; ++r) {
      int row = r0 + r;
      h2_s[(row << 7) + (colh ^ ((row & 7) << 3))] = (_Float16)h2n[r];
    }
    // next read of h2_s is after barrier pair of step t+1 -> safe
  }

  __syncthreads();  // final h2 writes visible; Whh1_s free for reuse

  // ================= MLP head: relu(h2 @ W1^T + b1) @ W2^T + b2 =================
  float* W1t = (float*)Whh1_s;          // [k][j] transposed, 64 KB
  float* m_s = (float*)x_s;             // [16][128] fp32, 8 KB
  for (int i = tid; i < H * H; i += NTHR) {
    int j = i >> 7, k = i & 127;
    W1t[(k << 7) + j] = W1[i];
  }
  __syncthreads();
  {
    const int s = tid >> 5;             // 0..15
    const int j0 = tid & 31;
    float a0 = 0.f, a1 = 0.f, a2 = 0.f, a3 = 0.f;
    for (int k = 0; k < H; ++k) {
      float hv = (float)h2_s[(s << 7) + (k ^ ((s & 7) << 3))];
      const float* wr = W1t + (k << 7) + j0;
      a0 += hv * wr[0]; a1 += hv * wr[32]; a2 += hv * wr[64]; a3 += hv * wr[96];
    }
    m_s[(s << 7) + j0     ] = fmaxf(a0 + b1v[j0     ], 0.f);
    m_s[(s << 7) + j0 + 32] = fmaxf(a1 + b1v[j0 + 32], 0.f);
    m_s[(s << 7) + j0 + 64] = fmaxf(a2 + b1v[j0 + 64], 0.f);
    m_s[(s << 7) + j0 + 96] = fmaxf(a3 + b1v[j0 + 96], 0.f);
  }
  __syncthreads();
  {
    const int s = tid >> 5;
    const int j0 = tid & 31;
    float part = 0.f;
    #pragma unroll
    for (int jj = 0; jj < 4; ++jj) {
      int j = j0 + (jj << 5);
      part += m_s[(s << 7) + j] * W2[j];
    }
    #pragma unroll
    for (int off = 16; off >= 1; off >>= 1) part += __shfl_xor(part, off, 32);
    if (j0 == 0)
      out_scores[sb + s] = part + b2v[0] + abias[(sb + s) & 63];
  }
}

// softmax over each row of 64 (one wave per row), in-place on d_out
__global__ void softmax_kernel(float* __restrict__ out) {
  const int b = blockIdx.x, n = threadIdx.x;
  float v = out[(b << 6) + n];
  float m = v;
  #pragma unroll
  for (int off = 32; off >= 1; off >>= 1) m = fmaxf(m, __shfl_xor(m, off, 64));
  float e = __builtin_amdgcn_exp2f((v - m) * 1.44269504089f);
  float s = e;
  #pragma unroll
  for (int off = 32; off >= 1; off >>= 1) s += __shfl_xor(s, off, 64);
  out[(b << 6) + n] = e / s;
}

extern "C" void kernel_launch(void* const* d_in, const int* in_sizes, int n_in,
                              void* d_out, int out_size, void* d_ws, size_t ws_size,
                              hipStream_t stream) {
  (void)in_sizes; (void)n_in; (void)d_ws; (void)ws_size; (void)out_size;
  const float* xg   = (const float*)d_in[0];
  const float* Wih0 = (const float*)d_in[1];
  const float* Whh0 = (const float*)d_in[2];
  const float* bih0 = (const float*)d_in[3];
  const float* bhh0 = (const float*)d_in[4];
  const float* Wih1 = (const float*)d_in[5];
  const float* Whh1 = (const float*)d_in[6];
  const float* bih1 = (const float*)d_in[7];
  const float* bhh1 = (const float*)d_in[8];
  const float* W1   = (const float*)d_in[9];
  const float* b1   = (const float*)d_in[10];
  const float* W2   = (const float*)d_in[11];
  const float* b2   = (const float*)d_in[12];
  const float* ab   = (const float*)d_in[13];
  float* out = (float*)d_out;

  lstm_kernel<<<NBLK, NTHR, 0, stream>>>(xg, Wih0, Whh0, bih0, bhh0,
                                         Wih1, Whh1, bih1, bhh1,
                                         W1, b1, W2, b2, ab, out);
  softmax_kernel<<<32, 64, 0, stream>>>(out);
}

// Round 3
// 506.600 us; speedup vs baseline: 1.3034x; 1.3034x over previous
//
#include <hip/hip_runtime.h>

#define H 128
#define L 256
#define SB 8       // sequences per block
#define NBLK 256   // 2048/SB -> one block per CU (LDS 152KB => 1 block/CU)
#define NTHR 512   // 8 waves; wave w owns gate-cols 16w..16w+15 of each gate tile

typedef _Float16 f16x8 __attribute__((ext_vector_type(8)));
typedef float f32x4 __attribute__((ext_vector_type(4)));

#define MFMA(accv, av, bv) accv = __builtin_amdgcn_mfma_f32_16x16x32_f16(av, bv, accv, 0, 0, 0)

__device__ __forceinline__ float fsig(float x) {
  return __builtin_amdgcn_rcpf(1.f + __builtin_amdgcn_exp2f(-1.44269504089f * x));
}
__device__ __forceinline__ float ftanh(float x) {
  return 2.f * __builtin_amdgcn_rcpf(1.f + __builtin_amdgcn_exp2f(-2.88539008178f * x)) - 1.f;
}

// Seq->MFMA-row map: seq s (0..7) lives at row 4*(s>>1)+(s&1); rows 4q+2,4q+3 are
// permanently zero. Every lane then owns 2 VALID acc rows (r=0,1) -> activation
// VALU per lane halves vs. packing seqs into rows 0..7.
// LDS f16 tiles [16][128] are XOR-swizzled: (row,k) -> row*128 + (k ^ ((row&7)<<3)).

__global__ __launch_bounds__(NTHR, 2) void lstm_kernel(
    const float* __restrict__ xg,
    const float* __restrict__ Wih0, const float* __restrict__ Whh0,
    const float* __restrict__ bih0, const float* __restrict__ bhh0,
    const float* __restrict__ Wih1, const float* __restrict__ Whh1,
    const float* __restrict__ bih1, const float* __restrict__ bhh1,
    const float* __restrict__ W1,   const float* __restrict__ b1v,
    const float* __restrict__ W2,   const float* __restrict__ b2v,
    const float* __restrict__ abias,
    float* __restrict__ out_scores)
{
  __shared__ __align__(16) _Float16 Whh1_s[512 * H];   // 128 KB, row-swizzled
  __shared__ __align__(16) float    x_s[L * SB];       // 8 KB, [t][s]
  __shared__ __align__(16) _Float16 h1_s[2][16 * H];   // 8 KB, double-buffered
  __shared__ __align__(16) _Float16 h2_s[2][16 * H];   // 8 KB

  const int tid  = threadIdx.x;
  const int lane = tid & 63;
  const int w    = tid >> 6;
  const int l15  = lane & 15;
  const int lhi  = lane >> 4;
  const int sb   = blockIdx.x * SB;

  // ---- stage x transposed [t][s] (coalesced global reads) ----
  for (int i = tid; i < SB * L; i += NTHR) {
    int s = i >> 8, t = i & 255;
    x_s[t * SB + s] = xg[(sb + s) * L + t];
  }
  // ---- stage W_hh1 as f16, swizzled ----
  for (int i = tid; i < 512 * H; i += NTHR) {
    int r = i >> 7, k = i & 127;
    Whh1_s[(r << 7) + (k ^ ((r & 7) << 3))] = (_Float16)Whh1[i];
  }
  // ---- zero h state, both buffers (LDS poisoned 0xAA) ----
  for (int i = tid; i < 16 * H; i += NTHR) {
    h1_s[0][i] = (_Float16)0.f; h1_s[1][i] = (_Float16)0.f;
    h2_s[0][i] = (_Float16)0.f; h2_s[1][i] = (_Float16)0.f;
  }

  // ---- per-wave register weight B-fragments ----
  // gate-tile n: cols c=(n<<7)+16w+l15 ; k = kk*32 + lhi*8 + j
  f16x8 whh0f[4][4], wih1f[4][4];
  float b0r[4], b1r[4], w0r[4];
  #pragma unroll
  for (int n = 0; n < 4; ++n) {
    const int c = (n << 7) + (w << 4) + l15;
    b0r[n] = bih0[c] + bhh0[c];
    b1r[n] = bih1[c] + bhh1[c];
    w0r[n] = Wih0[c];
    #pragma unroll
    for (int kk = 0; kk < 4; ++kk) {
      const float* p0 = Whh0 + c * H + (kk << 5) + (lhi << 3);
      const float* p1 = Wih1 + c * H + (kk << 5) + (lhi << 3);
      f16x8 f0, f1;
      #pragma unroll
      for (int j = 0; j < 8; ++j) { f0[j] = (_Float16)p0[j]; f1[j] = (_Float16)p1[j]; }
      whh0f[n][kk] = f0; wih1f[n][kk] = f1;
    }
  }

  float c1[2] = {0.f, 0.f}, c2[2] = {0.f, 0.f};
  const int colh  = (w << 4) | l15;     // gate-col (within 16-col tile) this lane writes
  const int rown0 = lhi << 2;           // owned rows: rown0, rown0+1
  const int so0   = lhi << 1;           // owned seqs: so0, so0+1
  const int arow  = l15 << 7;           // A-frag row base (lane reads row l15)
  const int aswz  = (l15 & 7) << 3;     // swizzle for row l15 / Whh1 row (colh&7==l15&7)
  int wrow[4];
  #pragma unroll
  for (int n = 0; n < 4; ++n) wrow[n] = ((n << 7) + colh) << 7;

  __syncthreads();

  #pragma unroll 1
  for (int t = 0; t < L; ++t) {
    const int cur = t & 1, prv = cur ^ 1;

    // prefetch A-frags of h1(t-1) and h2(t-1) (both ready since last barrier)
    f16x8 a1f[4], a2f[4];
    #pragma unroll
    for (int kk = 0; kk < 4; ++kk) {
      const int kb = (kk << 5) + (lhi << 3);
      a1f[kk] = *(const f16x8*)&h1_s[prv][arow + (kb ^ aswz)];
      a2f[kk] = *(const f16x8*)&h2_s[prv][arow + (kb ^ aswz)];
    }

    // ================= layer 0 =================
    f32x4 acc[4];
    #pragma unroll
    for (int n = 0; n < 4; ++n) acc[n] = (f32x4){0.f, 0.f, 0.f, 0.f};
    #pragma unroll
    for (int kk = 0; kk < 4; ++kk) {
      MFMA(acc[0], a1f[kk], whh0f[0][kk]);
      MFMA(acc[1], a1f[kk], whh0f[1][kk]);
      MFMA(acc[2], a1f[kk], whh0f[2][kk]);
      MFMA(acc[3], a1f[kk], whh0f[3][kk]);
    }

    const float2 xv = *(const float2*)&x_s[t * SB + so0];
    float h1n[2];
    #pragma unroll
    for (int r = 0; r < 2; ++r) {
      const float x0 = r ? xv.y : xv.x;
      float ig = fsig (acc[0][r] + x0 * w0r[0] + b0r[0]);
      float fg = fsig (acc[1][r] + x0 * w0r[1] + b0r[1]);
      float gg = ftanh(acc[2][r] + x0 * w0r[2] + b0r[2]);
      float og = fsig (acc[3][r] + x0 * w0r[3] + b0r[3]);
      float c = fg * c1[r] + ig * gg;
      c1[r] = c;
      h1n[r] = og * ftanh(c);
    }
    #pragma unroll
    for (int r = 0; r < 2; ++r) {
      const int row = rown0 + r;
      h1_s[cur][(row << 7) + (colh ^ ((row & 7) << 3))] = (_Float16)h1n[r];
    }
    __syncthreads();   // A: h1(t) visible; also orders h2(t-1) prefetch vs h2(t) write

    // ================= layer 1 =================
    #pragma unroll
    for (int n = 0; n < 4; ++n) acc[n] = (f32x4){0.f, 0.f, 0.f, 0.f};
    #pragma unroll
    for (int kk = 0; kk < 4; ++kk) {
      const int kb = (kk << 5) + (lhi << 3);
      f16x8 a = *(const f16x8*)&h1_s[cur][arow + (kb ^ aswz)];
      MFMA(acc[0], a, wih1f[0][kk]);
      MFMA(acc[1], a, wih1f[1][kk]);
      MFMA(acc[2], a, wih1f[2][kk]);
      MFMA(acc[3], a, wih1f[3][kk]);
    }
    #pragma unroll
    for (int kk = 0; kk < 4; ++kk) {
      const int kb = (kk << 5) + (lhi << 3);
      #pragma unroll
      for (int n = 0; n < 4; ++n) {
        f16x8 b = *(const f16x8*)&Whh1_s[wrow[n] + (kb ^ aswz)];
        MFMA(acc[n], a2f[kk], b);
      }
    }

    float h2n[2];
    #pragma unroll
    for (int r = 0; r < 2; ++r) {
      float ig = fsig (acc[0][r] + b1r[0]);
      float fg = fsig (acc[1][r] + b1r[1]);
      float gg = ftanh(acc[2][r] + b1r[2]);
      float og = fsig (acc[3][r] + b1r[3]);
      float c = fg * c2[r] + ig * gg;
      c2[r] = c;
      h2n[r] = og * ftanh(c);
    }
    #pragma unroll
    for (int r = 0; r < 2; ++r) {
      const int row = rown0 + r;
      h2_s[cur][(row << 7) + (colh ^ ((row & 7) << 3))] = (_Float16)h2n[r];
    }
    __syncthreads();   // B: h2(t) visible for next iter; protects buffer reuse
  }

  // ================= MLP head (fused, no m_s round-trip) =================
  // final h2 is in buffer (L-1)&1 == 1
  float* W1t = (float*)Whh1_s;          // [k][j] transposed fp32, 64 KB
  for (int i = tid; i < H * H; i += NTHR) {
    int j = i >> 7, k = i & 127;
    W1t[(k << 7) + j] = W1[i];
  }
  __syncthreads();
  {
    const int s   = w;                           // wave w <-> seq w
    const int row = ((s >> 1) << 2) | (s & 1);   // seq->row map
    float a0 = 0.f, a1 = 0.f;
    for (int k = 0; k < H; ++k) {
      float hv = (float)h2_s[1][(row << 7) + (k ^ ((row & 7) << 3))];  // broadcast
      a0 += hv * W1t[(k << 7) + lane];
      a1 += hv * W1t[(k << 7) + lane + 64];
    }
    a0 = fmaxf(a0 + b1v[lane], 0.f);
    a1 = fmaxf(a1 + b1v[lane + 64], 0.f);
    float part = a0 * W2[lane] + a1 * W2[lane + 64];
    #pragma unroll
    for (int off = 32; off >= 1; off >>= 1) part += __shfl_xor(part, off, 64);
    if (lane == 0)
      out_scores[sb + s] = part + b2v[0] + abias[(sb + s) & 63];
  }
}

// softmax over each row of 64 (one wave per row), in-place on d_out
__global__ void softmax_kernel(float* __restrict__ out) {
  const int b = blockIdx.x, n = threadIdx.x;
  float v = out[(b << 6) + n];
  float m = v;
  #pragma unroll
  for (int off = 32; off >= 1; off >>= 1) m = fmaxf(m, __shfl_xor(m, off, 64));
  float e = __builtin_amdgcn_exp2f((v - m) * 1.44269504089f);
  float s = e;
  #pragma unroll
  for (int off = 32; off >= 1; off >>= 1) s += __shfl_xor(s, off, 64);
  out[(b << 6) + n] = e / s;
}

extern "C" void kernel_launch(void* const* d_in, const int* in_sizes, int n_in,
                              void* d_out, int out_size, void* d_ws, size_t ws_size,
                              hipStream_t stream) {
  (void)in_sizes; (void)n_in; (void)d_ws; (void)ws_size; (void)out_size;
  const float* xg   = (const float*)d_in[0];
  const float* Wih0 = (const float*)d_in[1];
  const float* Whh0 = (const float*)d_in[2];
  const float* bih0 = (const float*)d_in[3];
  const float* bhh0 = (const float*)d_in[4];
  const float* Wih1 = (const float*)d_in[5];
  const float* Whh1 = (const float*)d_in[6];
  const float* bih1 = (const float*)d_in[7];
  const float* bhh1 = (const float*)d_in[8];
  const float* W1   = (const float*)d_in[9];
  const float* b1   = (const float*)d_in[10];
  const float* W2   = (const float*)d_in[11];
  const float* b2   = (const float*)d_in[12];
  const float* ab   = (const float*)d_in[13];
  float* out = (float*)d_out;

  lstm_kernel<<<NBLK, NTHR, 0, stream>>>(xg, Wih0, Whh0, bih0, bhh0,
                                         Wih1, Whh1, bih1, bhh1,
                                         W1, b1, W2, b2, ab, out);
  softmax_kernel<<<32, 64, 0, stream>>>(out);
}

// Round 4
// 474.817 us; speedup vs baseline: 1.3907x; 1.0669x over previous
//
#include <hip/hip_runtime.h>

#define H 128
#define L 256
#define SB 8       // sequences per block
#define NBLK 256   // 2048/SB -> one block per CU
#define NTHR 512   // 8 waves; wave w owns gate-cols 16w..16w+15 of each gate tile

typedef _Float16 f16x8 __attribute__((ext_vector_type(8)));
typedef float f32x4 __attribute__((ext_vector_type(4)));

#define MFMA(accv, av, bv) accv = __builtin_amdgcn_mfma_f32_16x16x32_f16(av, bv, accv, 0, 0, 0)

__device__ __forceinline__ float fsig(float x) {
  return __builtin_amdgcn_rcpf(1.f + __builtin_amdgcn_exp2f(-1.44269504089f * x));
}
__device__ __forceinline__ float ftanh(float x) {
  return 2.f * __builtin_amdgcn_rcpf(1.f + __builtin_amdgcn_exp2f(-2.88539008178f * x)) - 1.f;
}

// Skewed pipeline: phase t computes BOTH h1(t) = L0(x(t), h1(t-1)) and
// h2(t-1) = L1(h1(t-1), h2(t-2)). Both consume only state published at the
// end of phase t-1  ->  ONE barrier per phase, 257 phases (vs 512 barriers).
// Seq->MFMA-row map: seq s (0..7) at row 4*(s>>1)+(s&1); each lane owns 2
// valid acc rows. LDS f16 tiles swizzled: (row,k) -> row*128 + (k^((row&7)<<3)).

__global__ __launch_bounds__(NTHR, 2) void lstm_kernel(
    const float* __restrict__ xg,
    const float* __restrict__ Wih0, const float* __restrict__ Whh0,
    const float* __restrict__ bih0, const float* __restrict__ bhh0,
    const float* __restrict__ Wih1, const float* __restrict__ Whh1,
    const float* __restrict__ bih1, const float* __restrict__ bhh1,
    const float* __restrict__ W1,   const float* __restrict__ b1v,
    const float* __restrict__ W2,   const float* __restrict__ b2v,
    const float* __restrict__ abias,
    float* __restrict__ out_scores)
{
  __shared__ __align__(16) _Float16 Whh1_s[512 * H];   // 128 KB, row-swizzled
  __shared__ __align__(16) float    x_s[L * SB];       // 8 KB, [t][s]
  __shared__ __align__(16) _Float16 h1_s[2][16 * H];   // 8 KB, double-buffered
  __shared__ __align__(16) _Float16 h2_s[2][16 * H];   // 8 KB

  const int tid  = threadIdx.x;
  const int lane = tid & 63;
  const int w    = tid >> 6;
  const int l15  = lane & 15;
  const int lhi  = lane >> 4;
  const int sb   = blockIdx.x * SB;

  // ---- stage x transposed [t][s] ----
  for (int i = tid; i < SB * L; i += NTHR) {
    int s = i >> 8, t = i & 255;
    x_s[t * SB + s] = xg[(sb + s) * L + t];
  }
  // ---- stage W_hh1 as f16, swizzled ----
  for (int i = tid; i < 512 * H; i += NTHR) {
    int r = i >> 7, k = i & 127;
    Whh1_s[(r << 7) + (k ^ ((r & 7) << 3))] = (_Float16)Whh1[i];
  }
  // ---- zero h state, both buffers ----
  for (int i = tid; i < 16 * H; i += NTHR) {
    h1_s[0][i] = (_Float16)0.f; h1_s[1][i] = (_Float16)0.f;
    h2_s[0][i] = (_Float16)0.f; h2_s[1][i] = (_Float16)0.f;
  }

  // ---- per-wave register weight B-fragments ----
  f16x8 whh0f[4][4], wih1f[4][4];
  float b0r[4], b1r[4], w0r[4];
  #pragma unroll
  for (int n = 0; n < 4; ++n) {
    const int c = (n << 7) + (w << 4) + l15;
    b0r[n] = bih0[c] + bhh0[c];
    b1r[n] = bih1[c] + bhh1[c];
    w0r[n] = Wih0[c];
    #pragma unroll
    for (int kk = 0; kk < 4; ++kk) {
      const float* p0 = Whh0 + c * H + (kk << 5) + (lhi << 3);
      const float* p1 = Wih1 + c * H + (kk << 5) + (lhi << 3);
      f16x8 f0, f1;
      #pragma unroll
      for (int j = 0; j < 8; ++j) { f0[j] = (_Float16)p0[j]; f1[j] = (_Float16)p1[j]; }
      whh0f[n][kk] = f0; wih1f[n][kk] = f1;
    }
  }

  float c1[2] = {0.f, 0.f}, c2[2] = {0.f, 0.f};
  const int colh  = (w << 4) | l15;
  const int rown0 = lhi << 2;           // owned rows: rown0, rown0+1
  const int so0   = lhi << 1;           // owned seqs: so0, so0+1
  const int arow  = l15 << 7;           // A-frag row base
  const int aswz  = (l15 & 7) << 3;     // swizzle for row l15 / Whh1 row
  int wrow[4];
  #pragma unroll
  for (int n = 0; n < 4; ++n) wrow[n] = ((n << 7) + colh) << 7;

  __syncthreads();

  #pragma unroll 1
  for (int t = 0; t <= L; ++t) {
    const int pw = t & 1;        // h1 write buf; h2 READ buf (holds h2(t-2))
    const int pr = pw ^ 1;       // h1 read buf (h1(t-1)); h2 write buf (h2(t-1))

    // A-fragments: h1(t-1) and h2(t-2) — both published by last barrier
    f16x8 a1f[4], a2f[4];
    #pragma unroll
    for (int kk = 0; kk < 4; ++kk) {
      const int kb = (kk << 5) + (lhi << 3);
      a1f[kk] = *(const f16x8*)&h1_s[pr][arow + (kb ^ aswz)];
      a2f[kk] = *(const f16x8*)&h2_s[pw][arow + (kb ^ aswz)];
    }

    f32x4 acc0[4], acc1[4];
    #pragma unroll
    for (int n = 0; n < 4; ++n) {
      acc0[n] = (f32x4){0.f, 0.f, 0.f, 0.f};
      acc1[n] = (f32x4){0.f, 0.f, 0.f, 0.f};
    }

    // L0 gates (Whh0·h1) and L1a gates (Wih1·h1): 32 MFMA, reg B-operands,
    // all feed off a1f -> start as soon as a1f lands
    #pragma unroll
    for (int kk = 0; kk < 4; ++kk) {
      MFMA(acc0[0], a1f[kk], whh0f[0][kk]);
      MFMA(acc0[1], a1f[kk], whh0f[1][kk]);
      MFMA(acc0[2], a1f[kk], whh0f[2][kk]);
      MFMA(acc0[3], a1f[kk], whh0f[3][kk]);
      MFMA(acc1[0], a1f[kk], wih1f[0][kk]);
      MFMA(acc1[1], a1f[kk], wih1f[1][kk]);
      MFMA(acc1[2], a1f[kk], wih1f[2][kk]);
      MFMA(acc1[3], a1f[kk], wih1f[3][kk]);
    }
    // L1b gates (Whh1·h2), B streamed from LDS: 16 MFMA
    #pragma unroll
    for (int kk = 0; kk < 4; ++kk) {
      const int kb = (kk << 5) + (lhi << 3);
      #pragma unroll
      for (int n = 0; n < 4; ++n) {
        f16x8 b = *(const f16x8*)&Whh1_s[wrow[n] + (kb ^ aswz)];
        MFMA(acc1[n], a2f[kk], b);
      }
    }

    // ---- L0 activation -> h1(t) ----
    if (t < L) {
      const float2 xv = *(const float2*)&x_s[t * SB + so0];
      float h1n[2];
      #pragma unroll
      for (int r = 0; r < 2; ++r) {
        const float x0 = r ? xv.y : xv.x;
        float ig = fsig (acc0[0][r] + x0 * w0r[0] + b0r[0]);
        float fg = fsig (acc0[1][r] + x0 * w0r[1] + b0r[1]);
        float gg = ftanh(acc0[2][r] + x0 * w0r[2] + b0r[2]);
        float og = fsig (acc0[3][r] + x0 * w0r[3] + b0r[3]);
        float c = fg * c1[r] + ig * gg;
        c1[r] = c;
        h1n[r] = og * ftanh(c);
      }
      #pragma unroll
      for (int r = 0; r < 2; ++r) {
        const int row = rown0 + r;
        h1_s[pw][(row << 7) + (colh ^ ((row & 7) << 3))] = (_Float16)h1n[r];
      }
    }
    // ---- L1 activation -> h2(t-1) ----
    if (t > 0) {
      float h2n[2];
      #pragma unroll
      for (int r = 0; r < 2; ++r) {
        float ig = fsig (acc1[0][r] + b1r[0]);
        float fg = fsig (acc1[1][r] + b1r[1]);
        float gg = ftanh(acc1[2][r] + b1r[2]);
        float og = fsig (acc1[3][r] + b1r[3]);
        float c = fg * c2[r] + ig * gg;
        c2[r] = c;
        h2n[r] = og * ftanh(c);
      }
      #pragma unroll
      for (int r = 0; r < 2; ++r) {
        const int row = rown0 + r;
        h2_s[pr][(row << 7) + (colh ^ ((row & 7) << 3))] = (_Float16)h2n[r];
      }
    }
    __syncthreads();   // publish h1(t), h2(t-1); also orders buffer reuse
  }

  // ================= MLP head =================
  // final h2 = h2(L-1), written at phase L into h2_s[(L-1)&1] = h2_s[1]
  float* W1t = (float*)Whh1_s;          // [k][j] transposed fp32, 64 KB
  for (int i = tid; i < H * H; i += NTHR) {
    int j = i >> 7, k = i & 127;
    W1t[(k << 7) + j] = W1[i];
  }
  __syncthreads();
  {
    const int s   = w;                           // wave w <-> seq w
    const int row = ((s >> 1) << 2) | (s & 1);   // seq->row map
    float a0 = 0.f, a1 = 0.f;
    for (int k = 0; k < H; ++k) {
      float hv = (float)h2_s[1][(row << 7) + (k ^ ((row & 7) << 3))];  // broadcast
      a0 += hv * W1t[(k << 7) + lane];
      a1 += hv * W1t[(k << 7) + lane + 64];
    }
    a0 = fmaxf(a0 + b1v[lane], 0.f);
    a1 = fmaxf(a1 + b1v[lane + 64], 0.f);
    float part = a0 * W2[lane] + a1 * W2[lane + 64];
    #pragma unroll
    for (int off = 32; off >= 1; off >>= 1) part += __shfl_xor(part, off, 64);
    if (lane == 0)
      out_scores[sb + s] = part + b2v[0] + abias[(sb + s) & 63];
  }
}

// softmax over each row of 64 (one wave per row), in-place on d_out
__global__ void softmax_kernel(float* __restrict__ out) {
  const int b = blockIdx.x, n = threadIdx.x;
  float v = out[(b << 6) + n];
  float m = v;
  #pragma unroll
  for (int off = 32; off >= 1; off >>= 1) m = fmaxf(m, __shfl_xor(m, off, 64));
  float e = __builtin_amdgcn_exp2f((v - m) * 1.44269504089f);
  float s = e;
  #pragma unroll
  for (int off = 32; off >= 1; off >>= 1) s += __shfl_xor(s, off, 64);
  out[(b << 6) + n] = e / s;
}

extern "C" void kernel_launch(void* const* d_in, const int* in_sizes, int n_in,
                              void* d_out, int out_size, void* d_ws, size_t ws_size,
                              hipStream_t stream) {
  (void)in_sizes; (void)n_in; (void)d_ws; (void)ws_size; (void)out_size;
  const float* xg   = (const float*)d_in[0];
  const float* Wih0 = (const float*)d_in[1];
  const float* Whh0 = (const float*)d_in[2];
  const float* bih0 = (const float*)d_in[3];
  const float* bhh0 = (const float*)d_in[4];
  const float* Wih1 = (const float*)d_in[5];
  const float* Whh1 = (const float*)d_in[6];
  const float* bih1 = (const float*)d_in[7];
  const float* bhh1 = (const float*)d_in[8];
  const float* W1   = (const float*)d_in[9];
  const float* b1   = (const float*)d_in[10];
  const float* W2   = (const float*)d_in[11];
  const float* b2   = (const float*)d_in[12];
  const float* ab   = (const float*)d_in[13];
  float* out = (float*)d_out;

  lstm_kernel<<<NBLK, NTHR, 0, stream>>>(xg, Wih0, Whh0, bih0, bhh0,
                                         Wih1, Whh1, bih1, bhh1,
                                         W1, b1, W2, b2, ab, out);
  softmax_kernel<<<32, 64, 0, stream>>>(out);
}